// Round 5
// baseline (215.601 us; speedup 1.0000x reference)
//
#include <hip/hip_runtime.h>
#include <hip/hip_cooperative_groups.h>
#include <hip/hip_bf16.h>
#include <math.h>

namespace cg = cooperative_groups;

#define BB 16
#define NN 8192
#define DD 768
#define HH 3072
#define EPSV 1e-6f
#define DSQRT 0.03608439182435161f   // 768^-0.5

#define CHUNKS 64
#define ROWS_PER_BLOCK (NN / CHUNKS)              // 128
#define NWAVES 4
#define ROWS_PER_WAVE (ROWS_PER_BLOCK / NWAVES)   // 32
#define PSTRIDE 772                               // 768 pooled + 1 denom

#define KS1 16
#define KL1 (DD / KS1)    // 48
#define KS2 48
#define KL2 (HH / KS2)    // 64
#define CBLK 192          // cooperative grid size

// ---------------------------------------------------------------------------
// Kernel A (R3-proven config): single pass over x.
// ---------------------------------------------------------------------------
__global__ __launch_bounds__(256) void attn_pool_k(
    const float* __restrict__ x, const float* __restrict__ query,
    float* __restrict__ attn_out, float* __restrict__ partials)
{
    const int b     = blockIdx.y;
    const int chunk = blockIdx.x;
    const int tid   = threadIdx.x;
    const int wave  = tid >> 6;
    const int lane  = tid & 63;

    const float4* q4 = (const float4*)query;
    const float4 q0 = q4[lane];
    const float4 q1 = q4[lane + 64];
    const float4 q2 = q4[lane + 128];

    float4 p0 = make_float4(0.f, 0.f, 0.f, 0.f);
    float4 p1 = make_float4(0.f, 0.f, 0.f, 0.f);
    float4 p2 = make_float4(0.f, 0.f, 0.f, 0.f);
    float esum = 0.f;

    const int n0 = chunk * ROWS_PER_BLOCK + wave * ROWS_PER_WAVE;
    const float4* xb = (const float4*)(x + (size_t)b * NN * DD);

    #pragma unroll 2
    for (int r = 0; r < ROWS_PER_WAVE; ++r) {
        const int n = n0 + r;
        const float4* xr = xb + (size_t)n * (DD / 4);
        const float4 v0 = xr[lane];
        const float4 v1 = xr[lane + 64];
        const float4 v2 = xr[lane + 128];

        float s = v0.x * q0.x + v0.y * q0.y + v0.z * q0.z + v0.w * q0.w;
        s += v1.x * q1.x + v1.y * q1.y + v1.z * q1.z + v1.w * q1.w;
        s += v2.x * q2.x + v2.y * q2.y + v2.z * q2.z + v2.w * q2.w;
        #pragma unroll
        for (int off = 32; off > 0; off >>= 1) s += __shfl_xor(s, off);

        if (lane == 0) attn_out[(size_t)b * NN + n] = s;  // raw logit

        const float e = expf(s * DSQRT);
        esum += e;
        p0.x += e * v0.x; p0.y += e * v0.y; p0.z += e * v0.z; p0.w += e * v0.w;
        p1.x += e * v1.x; p1.y += e * v1.y; p1.z += e * v1.z; p1.w += e * v1.w;
        p2.x += e * v2.x; p2.y += e * v2.y; p2.z += e * v2.z; p2.w += e * v2.w;
    }

    __shared__ float lds[NWAVES][PSTRIDE];
    float* my = lds[wave];
    *(float4*)&my[lane * 4]       = p0;
    *(float4*)&my[256 + lane * 4] = p1;
    *(float4*)&my[512 + lane * 4] = p2;
    if (lane == 0) my[768] = esum;
    __syncthreads();

    float* outp = partials + (size_t)(b * CHUNKS + chunk) * PSTRIDE;
    #pragma unroll
    for (int k = 0; k < 3; ++k) {
        const int idx = tid + k * 256;
        outp[idx] = lds[0][idx] + lds[1][idx] + lds[2][idx] + lds[3][idx];
    }
    if (tid == 0) outp[768] = lds[0][768] + lds[1][768] + lds[2][768] + lds[3][768];
}

// ---------------------------------------------------------------------------
// Cooperative MLP kernel: all post-attn phases in one dispatch.
// 192 blocks x 256 threads, grid.sync() between phases. All reductions are
// fixed-order serial loops -> deterministic.
// ---------------------------------------------------------------------------
struct MlpParams {
    const float* partials;
    const float* gamma; const float* beta;
    const float* w1; const float* b1;
    const float* w2; const float* b2;
    float* qsum; float* qden;
    float* pooled; float* hln;
    float* g1p; float* h1; float* g2p;
    float* out;
};

__global__ __launch_bounds__(256) void mlp_coop_k(MlpParams P)
{
    cg::grid_group grid = cg::this_grid();
    const int bid = blockIdx.x;
    const int tid = threadIdx.x;
    __shared__ float smem[1024];

    // ---- P0: quarter-reduce partials over chunks (192 blocks) ----
    {
        const int b = bid / 12, r = bid % 12;
        const int slice = r % 3, q = r / 3;          // col-slice, chunk-quarter
        const float* pb = P.partials + (size_t)b * CHUNKS * PSTRIDE;
        const int col = slice * 256 + tid;
        float s = 0.f;
        #pragma unroll
        for (int c = 0; c < CHUNKS / 4; ++c) s += pb[(q * (CHUNKS / 4) + c) * PSTRIDE + col];
        P.qsum[(size_t)(b * 4 + q) * DD + col] = s;
        if (slice == 0 && tid == 0) {
            float dn = 0.f;
            #pragma unroll
            for (int c = 0; c < CHUNKS / 4; ++c) dn += pb[(q * (CHUNKS / 4) + c) * PSTRIDE + 768];
            P.qden[b * 4 + q] = dn;
        }
    }
    grid.sync();

    // ---- P1: softmax-normalize + LayerNorm (16 blocks) ----
    if (bid < BB) {
        const int b = bid;
        float v[3];
        #pragma unroll
        for (int k = 0; k < 3; ++k) {
            const int col = tid + k * 256;
            float s = 0.f;
            #pragma unroll
            for (int q = 0; q < 4; ++q) s += P.qsum[(size_t)(b * 4 + q) * DD + col];
            v[k] = s;
        }
        const float den = P.qden[b * 4] + P.qden[b * 4 + 1]
                        + P.qden[b * 4 + 2] + P.qden[b * 4 + 3];
        const float inv = 1.f / den;
        #pragma unroll
        for (int k = 0; k < 3; ++k) v[k] *= inv;

        smem[tid] = v[0] + v[1] + v[2];
        __syncthreads();
        for (int s = 128; s > 0; s >>= 1) {
            if (tid < s) smem[tid] += smem[tid + s];
            __syncthreads();
        }
        const float mu = smem[0] * (1.f / 768.f);
        __syncthreads();

        float sq = 0.f;
        #pragma unroll
        for (int k = 0; k < 3; ++k) { const float d = v[k] - mu; sq += d * d; }
        smem[tid] = sq;
        __syncthreads();
        for (int s = 128; s > 0; s >>= 1) {
            if (tid < s) smem[tid] += smem[tid + s];
            __syncthreads();
        }
        const float rstd = rsqrtf(smem[0] * (1.f / 768.f) + EPSV);

        #pragma unroll
        for (int k = 0; k < 3; ++k) {
            const int col = tid + k * 256;
            P.pooled[(size_t)b * DD + col] = v[k];
            P.hln[(size_t)b * DD + col] = (v[k] - mu) * rstd * P.gamma[col] + P.beta[col];
        }
    }
    grid.sync();

    // ---- P2: gemm1 K-split partial (192 blocks: 12 col-blocks x 16 ksplits) ----
    {
        const int jb = bid % 12, ks = bid / 12;
        const int k0 = ks * KL1;
        for (int i = tid; i < BB * KL1; i += 256)
            smem[i] = P.hln[(size_t)(i / KL1) * DD + k0 + (i % KL1)];
        __syncthreads();

        const int j = jb * 256 + tid;
        float wv[KL1];
        #pragma unroll
        for (int d = 0; d < KL1; ++d) wv[d] = P.w1[(size_t)(k0 + d) * HH + j];

        float acc[BB];
        #pragma unroll
        for (int b = 0; b < BB; ++b) acc[b] = 0.f;
        #pragma unroll
        for (int d4 = 0; d4 < KL1 / 4; ++d4) {
            #pragma unroll
            for (int b = 0; b < BB; ++b) {
                const float4 h4 = *(const float4*)&smem[b * KL1 + d4 * 4];
                acc[b] += h4.x * wv[d4 * 4] + h4.y * wv[d4 * 4 + 1]
                        + h4.z * wv[d4 * 4 + 2] + h4.w * wv[d4 * 4 + 3];
            }
        }
        #pragma unroll
        for (int b = 0; b < BB; ++b)
            P.g1p[((size_t)ks * BB + b) * HH + j] = acc[b];
        __syncthreads();
    }
    grid.sync();

    // ---- P3: combine + bias + exact gelu (192 blocks) ----
    {
        const int i = bid * 256 + tid;          // < 49152
        const int j = i % HH;
        float a = P.b1[j];
        #pragma unroll
        for (int s = 0; s < KS1; ++s) a += P.g1p[(size_t)s * BB * HH + i];
        P.h1[i] = 0.5f * a * (1.f + erff(a * 0.70710678118654752f));
    }
    grid.sync();

    // ---- P4: gemm2 K-split partial (144 blocks: 3 col-blocks x 48 ksplits) ----
    if (bid < 144) {
        const int cb = bid % 3, ks = bid / 3;
        const int k0 = ks * KL2;
        for (int i = tid; i < BB * KL2; i += 256)
            smem[i] = P.h1[(size_t)(i / KL2) * HH + k0 + (i % KL2)];
        __syncthreads();

        const int col = cb * 256 + tid;
        float wv[KL2];
        #pragma unroll
        for (int d = 0; d < KL2; ++d) wv[d] = P.w2[(size_t)(k0 + d) * DD + col];

        float acc[BB];
        #pragma unroll
        for (int b = 0; b < BB; ++b) acc[b] = 0.f;
        #pragma unroll
        for (int d4 = 0; d4 < KL2 / 4; ++d4) {
            #pragma unroll
            for (int b = 0; b < BB; ++b) {
                const float4 h4 = *(const float4*)&smem[b * KL2 + d4 * 4];
                acc[b] += h4.x * wv[d4 * 4] + h4.y * wv[d4 * 4 + 1]
                        + h4.z * wv[d4 * 4 + 2] + h4.w * wv[d4 * 4 + 3];
            }
        }
        #pragma unroll
        for (int b = 0; b < BB; ++b)
            P.g2p[((size_t)ks * BB + b) * DD + col] = acc[b];
    }
    grid.sync();

    // ---- P5: final combine (48 blocks) ----
    if (bid < 48) {
        const int i = bid * 256 + tid;          // < 12288
        const int d = i % DD;
        float a = P.pooled[i] + P.b2[d];
        #pragma unroll
        for (int s = 0; s < KS2; ++s) a += P.g2p[(size_t)s * BB * DD + i];
        P.out[i] = a;
    }
}

extern "C" void kernel_launch(void* const* d_in, const int* in_sizes, int n_in,
                              void* d_out, int out_size, void* d_ws, size_t ws_size,
                              hipStream_t stream)
{
    const float* x     = (const float*)d_in[0];
    const float* query = (const float*)d_in[1];
    const float* gamma = (const float*)d_in[2];
    const float* beta  = (const float*)d_in[3];
    const float* w1    = (const float*)d_in[4];
    const float* b1    = (const float*)d_in[5];
    const float* w2    = (const float*)d_in[6];
    const float* b2    = (const float*)d_in[7];

    float* out      = (float*)d_out;       // [16][768]
    float* attn_out = out + BB * DD;       // [16][8192] raw logits

    float* ws       = (float*)d_ws;
    float* partials = ws;                               // 16*64*772
    float* qsum     = partials + BB * CHUNKS * PSTRIDE; // 16*4*768
    float* qden     = qsum + BB * 4 * DD;               // 64
    float* pooled   = qden + 64;
    float* hln      = pooled + BB * DD;
    float* h1       = hln + BB * DD;                    // 16*3072
    float* g1p      = h1 + BB * HH;                     // 16*16*3072
    float* g2p      = g1p + KS1 * BB * HH;              // 48*16*768

    attn_pool_k<<<dim3(CHUNKS, BB), 256, 0, stream>>>(x, query, attn_out, partials);

    MlpParams p;
    p.partials = partials; p.gamma = gamma; p.beta = beta;
    p.w1 = w1; p.b1 = b1; p.w2 = w2; p.b2 = b2;
    p.qsum = qsum; p.qden = qden; p.pooled = pooled; p.hln = hln;
    p.g1p = g1p; p.h1 = h1; p.g2p = g2p; p.out = out;
    void* kargs[] = { (void*)&p };
    hipLaunchCooperativeKernel((void*)mlp_coop_k, dim3(CBLK), dim3(256),
                               kargs, 0, stream);
}

// Round 6
// 109.551 us; speedup vs baseline: 1.9681x; 1.9681x over previous
//
#include <hip/hip_runtime.h>
#include <hip/hip_bf16.h>
#include <math.h>

#define BB 16
#define NN 8192
#define DD 768
#define HH 3072
#define EPSV 1e-6f
#define DSQRT 0.03608439182435161f   // 768^-0.5

#define CHUNKS 64
#define ROWS_PER_BLOCK (NN / CHUNKS)              // 128
#define NWAVES 4
#define ROWS_PER_WAVE (ROWS_PER_BLOCK / NWAVES)   // 32
#define PSTRIDE 772                               // 768 pooled + 1 denom
#define QQ 4                                      // chunk quarters

#define KS1 16
#define KL1 (DD / KS1)    // 48
#define KS2 48
#define KL2 (HH / KS2)    // 64

// ---------------------------------------------------------------------------
// Kernel A (byte-identical to R3 best): single pass over x.
// ---------------------------------------------------------------------------
__global__ __launch_bounds__(256) void attn_pool_k(
    const float* __restrict__ x, const float* __restrict__ query,
    float* __restrict__ attn_out, float* __restrict__ partials)
{
    const int b     = blockIdx.y;
    const int chunk = blockIdx.x;
    const int tid   = threadIdx.x;
    const int wave  = tid >> 6;
    const int lane  = tid & 63;

    const float4* q4 = (const float4*)query;
    const float4 q0 = q4[lane];
    const float4 q1 = q4[lane + 64];
    const float4 q2 = q4[lane + 128];

    float4 p0 = make_float4(0.f, 0.f, 0.f, 0.f);
    float4 p1 = make_float4(0.f, 0.f, 0.f, 0.f);
    float4 p2 = make_float4(0.f, 0.f, 0.f, 0.f);
    float esum = 0.f;

    const int n0 = chunk * ROWS_PER_BLOCK + wave * ROWS_PER_WAVE;
    const float4* xb = (const float4*)(x + (size_t)b * NN * DD);

    #pragma unroll 2
    for (int r = 0; r < ROWS_PER_WAVE; ++r) {
        const int n = n0 + r;
        const float4* xr = xb + (size_t)n * (DD / 4);
        const float4 v0 = xr[lane];
        const float4 v1 = xr[lane + 64];
        const float4 v2 = xr[lane + 128];

        float s = v0.x * q0.x + v0.y * q0.y + v0.z * q0.z + v0.w * q0.w;
        s += v1.x * q1.x + v1.y * q1.y + v1.z * q1.z + v1.w * q1.w;
        s += v2.x * q2.x + v2.y * q2.y + v2.z * q2.z + v2.w * q2.w;
        #pragma unroll
        for (int off = 32; off > 0; off >>= 1) s += __shfl_xor(s, off);

        if (lane == 0) attn_out[(size_t)b * NN + n] = s;  // raw logit

        const float e = expf(s * DSQRT);
        esum += e;
        p0.x += e * v0.x; p0.y += e * v0.y; p0.z += e * v0.z; p0.w += e * v0.w;
        p1.x += e * v1.x; p1.y += e * v1.y; p1.z += e * v1.z; p1.w += e * v1.w;
        p2.x += e * v2.x; p2.y += e * v2.y; p2.z += e * v2.z; p2.w += e * v2.w;
    }

    __shared__ float lds[NWAVES][PSTRIDE];
    float* my = lds[wave];
    *(float4*)&my[lane * 4]       = p0;
    *(float4*)&my[256 + lane * 4] = p1;
    *(float4*)&my[512 + lane * 4] = p2;
    if (lane == 0) my[768] = esum;
    __syncthreads();

    float* outp = partials + (size_t)(b * CHUNKS + chunk) * PSTRIDE;
    #pragma unroll
    for (int k = 0; k < 3; ++k) {
        const int idx = tid + k * 256;
        outp[idx] = lds[0][idx] + lds[1][idx] + lds[2][idx] + lds[3][idx];
    }
    if (tid == 0) outp[768] = lds[0][768] + lds[1][768] + lds[2][768] + lds[3][768];
}

// ---------------------------------------------------------------------------
// Kernel B0: wide quarter-reduce of partials. grid (12, 16) = 192 blocks.
// blockIdx.x -> slice (0..2) x quarter (0..3). Fixed-order sums.
// ---------------------------------------------------------------------------
__global__ __launch_bounds__(256) void qreduce_k(
    const float* __restrict__ partials, float* __restrict__ qsum,
    float* __restrict__ qden)
{
    const int slice = blockIdx.x % 3;
    const int q     = blockIdx.x / 3;
    const int b     = blockIdx.y;
    const int tid   = threadIdx.x;
    const float* pb = partials + (size_t)b * CHUNKS * PSTRIDE;

    const int col = slice * 256 + tid;
    float s = 0.f;
    #pragma unroll
    for (int c = 0; c < CHUNKS / QQ; ++c)
        s += pb[(q * (CHUNKS / QQ) + c) * PSTRIDE + col];
    qsum[(size_t)(b * QQ + q) * DD + col] = s;

    if (slice == 0 && tid < CHUNKS / QQ) {   // 16 lanes, parallel denom reduce
        float dn = pb[(q * (CHUNKS / QQ) + tid) * PSTRIDE + 768];
        #pragma unroll
        for (int off = 8; off > 0; off >>= 1) dn += __shfl_xor(dn, off, 16);
        if (tid == 0) qden[b * QQ + q] = dn;
    }
}

// ---------------------------------------------------------------------------
// Kernel B1: final reduce (196 KB) + softmax-normalize + LayerNorm.
// 16 blocks x 768 threads.
// ---------------------------------------------------------------------------
__global__ __launch_bounds__(768) void reduce_ln_k(
    const float* __restrict__ qsum, const float* __restrict__ qden,
    const float* __restrict__ gamma, const float* __restrict__ beta,
    float* __restrict__ pooled_ws, float* __restrict__ hln_ws)
{
    const int b = blockIdx.x, tid = threadIdx.x;   // tid < 768

    float v = 0.f;
    #pragma unroll
    for (int q = 0; q < QQ; ++q) v += qsum[(size_t)(b * QQ + q) * DD + tid];

    const float den = qden[b * QQ] + qden[b * QQ + 1]
                    + qden[b * QQ + 2] + qden[b * QQ + 3];
    v *= (1.f / den);

    __shared__ float red[768];
    red[tid] = v;
    __syncthreads();
    if (tid < 256) red[tid] += red[tid + 256] + red[tid + 512];
    __syncthreads();
    for (int s = 128; s > 0; s >>= 1) {
        if (tid < s) red[tid] += red[tid + s];
        __syncthreads();
    }
    const float mu = red[0] * (1.f / 768.f);
    __syncthreads();

    const float dmu = v - mu;
    red[tid] = dmu * dmu;
    __syncthreads();
    if (tid < 256) red[tid] += red[tid + 256] + red[tid + 512];
    __syncthreads();
    for (int s = 128; s > 0; s >>= 1) {
        if (tid < s) red[tid] += red[tid + s];
        __syncthreads();
    }
    const float var = red[0] * (1.f / 768.f);
    const float rstd = rsqrtf(var + EPSV);

    pooled_ws[(size_t)b * DD + tid] = v;
    hln_ws[(size_t)b * DD + tid] = (v - mu) * rstd * gamma[tid] + beta[tid];
}

// ---------------------------------------------------------------------------
// Kernel C: B-major K-split partial of hln @ w1. grid (12, 16) = 192 blocks.
// ---------------------------------------------------------------------------
__global__ __launch_bounds__(256) void gemm1_part_k(
    const float* __restrict__ hln_ws, const float* __restrict__ w1,
    float* __restrict__ g1p)
{
    const int j  = blockIdx.x * 256 + threadIdx.x;  // hidden column
    const int k0 = blockIdx.y * KL1;                // K offset

    __shared__ float hl[BB][KL1];
    for (int i = threadIdx.x; i < BB * KL1; i += 256) {
        const int b = i / KL1, d = i - b * KL1;
        hl[b][d] = hln_ws[(size_t)b * DD + k0 + d];
    }
    __syncthreads();

    float wv[KL1];
    #pragma unroll
    for (int d = 0; d < KL1; ++d) wv[d] = w1[(size_t)(k0 + d) * HH + j];

    float acc[BB];
    #pragma unroll
    for (int b = 0; b < BB; ++b) acc[b] = 0.f;

    #pragma unroll
    for (int d4 = 0; d4 < KL1 / 4; ++d4) {
        #pragma unroll
        for (int b = 0; b < BB; ++b) {
            const float4 h4 = *(const float4*)&hl[b][d4 * 4];
            acc[b] += h4.x * wv[d4 * 4] + h4.y * wv[d4 * 4 + 1]
                    + h4.z * wv[d4 * 4 + 2] + h4.w * wv[d4 * 4 + 3];
        }
    }

    float* op = g1p + (size_t)blockIdx.y * BB * HH;   // [ks][b][HH]
    #pragma unroll
    for (int b = 0; b < BB; ++b) op[(size_t)b * HH + j] = acc[b];
}

// ---------------------------------------------------------------------------
// Kernel D: combine K-split partials + bias + exact gelu. 192 blocks.
// ---------------------------------------------------------------------------
__global__ __launch_bounds__(256) void comb1_gelu_k(
    const float* __restrict__ g1p, const float* __restrict__ b1,
    float* __restrict__ h1_ws)
{
    const int i = blockIdx.x * 256 + threadIdx.x;   // < 16*3072
    const int j = i % HH;

    float a = b1[j];
    #pragma unroll
    for (int s = 0; s < KS1; ++s) a += g1p[(size_t)s * BB * HH + i];
    h1_ws[i] = 0.5f * a * (1.f + erff(a * 0.70710678118654752f));
}

// ---------------------------------------------------------------------------
// Kernel E: B-major K-split partial of h1 @ w2. grid (3, 48) = 144 blocks.
// ---------------------------------------------------------------------------
__global__ __launch_bounds__(256) void gemm2_part_k(
    const float* __restrict__ h1_ws, const float* __restrict__ w2,
    float* __restrict__ g2p)
{
    const int col = blockIdx.x * 256 + threadIdx.x;  // out column
    const int k0  = blockIdx.y * KL2;                // K offset

    __shared__ float hg[BB][KL2];
    for (int i = threadIdx.x; i < BB * KL2; i += 256) {
        const int b = i / KL2, d = i - b * KL2;
        hg[b][d] = h1_ws[(size_t)b * HH + k0 + d];
    }
    __syncthreads();

    float wv[KL2];
    #pragma unroll
    for (int d = 0; d < KL2; ++d) wv[d] = w2[(size_t)(k0 + d) * DD + col];

    float acc[BB];
    #pragma unroll
    for (int b = 0; b < BB; ++b) acc[b] = 0.f;

    #pragma unroll
    for (int d4 = 0; d4 < KL2 / 4; ++d4) {
        #pragma unroll
        for (int b = 0; b < BB; ++b) {
            const float4 h4 = *(const float4*)&hg[b][d4 * 4];
            acc[b] += h4.x * wv[d4 * 4] + h4.y * wv[d4 * 4 + 1]
                    + h4.z * wv[d4 * 4 + 2] + h4.w * wv[d4 * 4 + 3];
        }
    }

    float* op = g2p + (size_t)blockIdx.y * BB * DD;   // [ks][b][DD]
    #pragma unroll
    for (int b = 0; b < BB; ++b) op[(size_t)b * DD + col] = acc[b];
}

// ---------------------------------------------------------------------------
// Kernel F: out = pooled + b2 + sum_s g2p. 48 blocks.
// ---------------------------------------------------------------------------
__global__ __launch_bounds__(256) void comb2_fin_k(
    const float* __restrict__ g2p, const float* __restrict__ pooled_ws,
    const float* __restrict__ b2, float* __restrict__ out)
{
    const int i = blockIdx.x * 256 + threadIdx.x;   // < 12288
    const int d = i % DD;

    float a = pooled_ws[i] + b2[d];
    #pragma unroll
    for (int s = 0; s < KS2; ++s) a += g2p[(size_t)s * BB * DD + i];
    out[i] = a;
}

extern "C" void kernel_launch(void* const* d_in, const int* in_sizes, int n_in,
                              void* d_out, int out_size, void* d_ws, size_t ws_size,
                              hipStream_t stream)
{
    const float* x     = (const float*)d_in[0];
    const float* query = (const float*)d_in[1];
    const float* gamma = (const float*)d_in[2];
    const float* beta  = (const float*)d_in[3];
    const float* w1    = (const float*)d_in[4];
    const float* b1    = (const float*)d_in[5];
    const float* w2    = (const float*)d_in[6];
    const float* b2    = (const float*)d_in[7];

    float* out      = (float*)d_out;       // [16][768]
    float* attn_out = out + BB * DD;       // [16][8192] raw logits

    float* ws       = (float*)d_ws;
    float* partials = ws;                               // 16*64*772
    float* qsum     = partials + BB * CHUNKS * PSTRIDE; // 16*4*768
    float* qden     = qsum + BB * QQ * DD;              // 64
    float* pooled   = qden + 64;
    float* hln      = pooled + BB * DD;
    float* h1       = hln + BB * DD;                    // 16*3072
    float* g1p      = h1 + BB * HH;                     // 16*16*3072
    float* g2p      = g1p + KS1 * BB * HH;              // 48*16*768

    attn_pool_k<<<dim3(CHUNKS, BB), 256, 0, stream>>>(x, query, attn_out, partials);
    qreduce_k<<<dim3(12, BB), 256, 0, stream>>>(partials, qsum, qden);
    reduce_ln_k<<<dim3(BB), 768, 0, stream>>>(qsum, qden, gamma, beta, pooled, hln);
    gemm1_part_k<<<dim3(HH / 256, KS1), 256, 0, stream>>>(hln, w1, g1p);
    comb1_gelu_k<<<dim3(BB * HH / 256), 256, 0, stream>>>(g1p, b1, h1);
    gemm2_part_k<<<dim3(DD / 256, KS2), 256, 0, stream>>>(h1, w2, g2p);
    comb2_fin_k<<<dim3(BB * DD / 256), 256, 0, stream>>>(g2p, pooled, b2, out);
}